// Round 1
// baseline (1508.673 us; speedup 1.0000x reference)
//
#include <hip/hip_runtime.h>
#include <stdint.h>

#define DIM 1024
#define HID 1024
#define NE 8
#define NTOK 32768
#define MCAP (2*NTOK + NE*128)   /* 66560 rows: 65536 gathered + worst-case pad */
#define MAXTILES (MCAP/128)      /* 520 */

typedef unsigned short u16;
typedef short bf16x8 __attribute__((ext_vector_type(8)));
typedef float f32x4  __attribute__((ext_vector_type(4)));
typedef u16 u16x8 __attribute__((ext_vector_type(8)));

__device__ __forceinline__ u16 f2b(float f) {
  uint32_t u = __float_as_uint(f);
  return (u16)((u + 0x7fffu + ((u >> 16) & 1u)) >> 16);   // RNE f32->bf16
}

__device__ __forceinline__ void gload16(const void* g, void* l) {
  __builtin_amdgcn_global_load_lds(
      (const __attribute__((address_space(1))) unsigned int*)g,
      (__attribute__((address_space(3))) unsigned int*)l, 16, 0, 0);
}

// ---------------- f32 -> bf16 bulk convert (8 elems/thread/iter) ----------------
__global__ __launch_bounds__(256) void cvt_kernel(const float* __restrict__ s,
                                                  u16* __restrict__ d, int n8) {
  int i = blockIdx.x * blockDim.x + threadIdx.x;
  int str = gridDim.x * blockDim.x;
  for (; i < n8; i += str) {
    const float4* sp = (const float4*)s + (size_t)i * 2;
    float4 a = sp[0], b = sp[1];
    u16x8 o;
    o[0] = f2b(a.x); o[1] = f2b(a.y); o[2] = f2b(a.z); o[3] = f2b(a.w);
    o[4] = f2b(b.x); o[5] = f2b(b.y); o[6] = f2b(b.z); o[7] = f2b(b.w);
    *(u16x8*)(d + (size_t)i * 8) = o;
  }
}

// ---------------- router: f64 logits, top-2, normalized sigmoid weights --------
__global__ __launch_bounds__(256) void router_kernel(
    const float* __restrict__ x, const float* __restrict__ gw,
    int2* __restrict__ tokE, float2* __restrict__ tokW, int* __restrict__ counts) {
  __shared__ int lcnt[NE];
  if (threadIdx.x < NE) lcnt[threadIdx.x] = 0;
  __syncthreads();
  const int wid = threadIdx.x >> 6, lane = threadIdx.x & 63;
  for (int j = 0; j < 8; ++j) {
    const int t = (blockIdx.x * 4 + wid) * 8 + j;
    const float4* xp = (const float4*)(x + (size_t)t * DIM);
    float4 xv[4];
#pragma unroll
    for (int c = 0; c < 4; ++c) xv[c] = xp[lane + 64 * c];
    double acc[NE];
#pragma unroll
    for (int e = 0; e < NE; ++e) {
      const float4* gp = (const float4*)(gw + e * DIM);
      double s = 0.0;
#pragma unroll
      for (int c = 0; c < 4; ++c) {
        float4 g = gp[lane + 64 * c];
        s += (double)xv[c].x * g.x + (double)xv[c].y * g.y +
             (double)xv[c].z * g.z + (double)xv[c].w * g.w;
      }
      acc[e] = s;
    }
#pragma unroll
    for (int e = 0; e < NE; ++e)
      for (int o = 32; o > 0; o >>= 1) acc[e] += __shfl_xor(acc[e], o);
    if (lane == 0) {
      int e0 = 0; double v0 = acc[0];
#pragma unroll
      for (int e = 1; e < NE; ++e) if (acc[e] > v0) { v0 = acc[e]; e0 = e; }
      int e1 = -1; double v1 = -1e300;
#pragma unroll
      for (int e = 0; e < NE; ++e) if (e != e0 && acc[e] > v1) { v1 = acc[e]; e1 = e; }
      float s0 = 1.f / (1.f + __expf(-(float)v0));
      float s1 = 1.f / (1.f + __expf(-(float)v1));
      float inv = 1.f / (s0 + s1 + 1e-9f);
      atomicAdd(&lcnt[e0], 1); atomicAdd(&lcnt[e1], 1);
      tokE[t] = make_int2(e0, e1);
      tokW[t] = make_float2(s0 * inv, s1 * inv);
    }
  }
  __syncthreads();
  if (threadIdx.x < NE) atomicAdd(&counts[threadIdx.x], lcnt[threadIdx.x]);
}

// ---------------- prefix (padded to 128) + tile table ----------------
__global__ void setup_kernel(const int* __restrict__ counts, int* __restrict__ off9,
                             int* __restrict__ ntiles, int* __restrict__ tileE,
                             int* __restrict__ tileB) {
  __shared__ int soff[NE + 1];
  if (threadIdx.x == 0) {
    int a = 0;
    for (int e = 0; e < NE; ++e) { soff[e] = a; a += ((counts[e] + 127) >> 7) << 7; }
    soff[NE] = a;
    for (int i = 0; i <= NE; ++i) off9[i] = soff[i];
    *ntiles = a >> 7;
  }
  __syncthreads();
  const int nt = soff[NE] >> 7;
  for (int i = threadIdx.x; i < nt; i += blockDim.x) {
    int r = i << 7, e = 0;
    while (r >= soff[e + 1]) ++e;
    tileE[i] = e; tileB[i] = r;
  }
}

// ---------------- scatter tokens into expert segments ----------------
__global__ __launch_bounds__(256) void scatter_kernel(
    const int2* __restrict__ tokE, const float2* __restrict__ tokW,
    const int* __restrict__ off9, int* __restrict__ cursors,
    int* __restrict__ rowidx, float* __restrict__ roww) {
  __shared__ int lcnt[NE], lbase[NE];
  if (threadIdx.x < NE) lcnt[threadIdx.x] = 0;
  __syncthreads();
  const int t = blockIdx.x * 256 + threadIdx.x;
  int2 e = tokE[t]; float2 w = tokW[t];
  int p0 = atomicAdd(&lcnt[e.x], 1);
  int p1 = atomicAdd(&lcnt[e.y], 1);
  __syncthreads();
  if (threadIdx.x < NE) lbase[threadIdx.x] = atomicAdd(&cursors[threadIdx.x], lcnt[threadIdx.x]);
  __syncthreads();
  int r0 = off9[e.x] + lbase[e.x] + p0;
  rowidx[r0] = t; roww[r0] = w.x;
  int r1 = off9[e.y] + lbase[e.y] + p1;
  rowidx[r1] = t; roww[r1] = w.y;
}

// ---------------- GEMM1: h = silu(A Wg^T) * (A Wu^T), gathered A -------------
__global__ __launch_bounds__(256) void gemm1_kernel(
    const u16* __restrict__ xb, const u16* __restrict__ wgb, const u16* __restrict__ wub,
    const int* __restrict__ rowidx, const int* __restrict__ ntiles,
    const int* __restrict__ tileE, const int* __restrict__ tileB,
    const u16* __restrict__ zrow, u16* __restrict__ hbuf) {
  if ((int)blockIdx.y >= *ntiles) return;
  const int e = tileE[blockIdx.y];
  const int mbase = tileB[blockIdx.y];
  const int nbase = blockIdx.x * 128;

  __shared__ __align__(16) u16 lA[128][64];
  __shared__ __align__(16) u16 lG[128][64];
  __shared__ __align__(16) u16 lU[128][64];

  const int tid = threadIdx.x;
  const int srow = tid >> 3;            // 0..31
  const int scol = (tid & 7) << 3;      // 0..56 (elements)

  const u16* asrc[4];
#pragma unroll
  for (int i = 0; i < 4; ++i) {
    int tok = rowidx[mbase + srow + i * 32];
    asrc[i] = (tok >= 0) ? (xb + (size_t)tok * DIM + scol) : (zrow + scol);
  }
  const u16* gsrc = wgb + (size_t)e * HID * DIM + (size_t)(nbase + srow) * DIM + scol;
  const u16* usrc = wub + (size_t)e * HID * DIM + (size_t)(nbase + srow) * DIM + scol;

  const int wid = tid >> 6, lane = tid & 63;
  const int wr = (wid >> 1) << 6;
  const int wc = (wid & 1) << 6;
  const int fr = lane & 15;
  const int fq = lane >> 4;

  const f32x4 fzero = {0.f, 0.f, 0.f, 0.f};
  f32x4 accG[4][4], accU[4][4];
#pragma unroll
  for (int m = 0; m < 4; ++m)
#pragma unroll
    for (int n = 0; n < 4; ++n) { accG[m][n] = fzero; accU[m][n] = fzero; }

  for (int k0 = 0; k0 < DIM; k0 += 64) {
    __syncthreads();
#pragma unroll
    for (int i = 0; i < 4; ++i) gload16(asrc[i] + k0, &lA[srow + i * 32][scol]);
#pragma unroll
    for (int i = 0; i < 4; ++i) gload16(gsrc + (size_t)i * 32 * DIM + k0, &lG[srow + i * 32][scol]);
#pragma unroll
    for (int i = 0; i < 4; ++i) gload16(usrc + (size_t)i * 32 * DIM + k0, &lU[srow + i * 32][scol]);
    __syncthreads();
#pragma unroll
    for (int ks = 0; ks < 64; ks += 32) {
      const int kc = ks + (fq << 3);
      bf16x8 af[4], gf[4], uf[4];
#pragma unroll
      for (int m = 0; m < 4; ++m) af[m] = *(const bf16x8*)&lA[wr + m * 16 + fr][kc];
#pragma unroll
      for (int n = 0; n < 4; ++n) gf[n] = *(const bf16x8*)&lG[wc + n * 16 + fr][kc];
#pragma unroll
      for (int n = 0; n < 4; ++n) uf[n] = *(const bf16x8*)&lU[wc + n * 16 + fr][kc];
#pragma unroll
      for (int m = 0; m < 4; ++m)
#pragma unroll
        for (int n = 0; n < 4; ++n) {
          accG[m][n] = __builtin_amdgcn_mfma_f32_16x16x32_bf16(af[m], gf[n], accG[m][n], 0, 0, 0);
          accU[m][n] = __builtin_amdgcn_mfma_f32_16x16x32_bf16(af[m], uf[n], accU[m][n], 0, 0, 0);
        }
    }
  }
  // epilogue: silu(g)*u -> bf16 h (C/D layout: col=lane&15, row=fq*4+r)
#pragma unroll
  for (int m = 0; m < 4; ++m) {
#pragma unroll
    for (int r = 0; r < 4; ++r) {
      const int row = mbase + wr + m * 16 + (fq << 2) + r;
      u16* hp = hbuf + (size_t)row * HID + nbase + wc + fr;
#pragma unroll
      for (int n = 0; n < 4; ++n) {
        float g = accG[m][n][r], u = accU[m][n][r];
        float hv = g * u / (1.f + __expf(-g));
        hp[n * 16] = f2b(hv);
      }
    }
  }
}

// ---------------- GEMM2: out[tok] += w * (h Wd^T) ----------------
__global__ __launch_bounds__(256) void gemm2_kernel(
    const u16* __restrict__ hbuf, const u16* __restrict__ wdb,
    const int* __restrict__ rowidx, const float* __restrict__ roww,
    const int* __restrict__ ntiles, const int* __restrict__ tileE,
    const int* __restrict__ tileB, float* __restrict__ out) {
  if ((int)blockIdx.y >= *ntiles) return;
  const int e = tileE[blockIdx.y];
  const int mbase = tileB[blockIdx.y];
  const int nbase = blockIdx.x * 128;

  __shared__ __align__(16) u16 lA[128][64];
  __shared__ __align__(16) u16 lB[128][64];

  const int tid = threadIdx.x;
  const int srow = tid >> 3;
  const int scol = (tid & 7) << 3;
  const u16* asrc = hbuf + (size_t)(mbase + srow) * HID + scol;
  const u16* bsrc = wdb + (size_t)e * DIM * HID + (size_t)(nbase + srow) * HID + scol;

  const int wid = tid >> 6, lane = tid & 63;
  const int wr = (wid >> 1) << 6;
  const int wc = (wid & 1) << 6;
  const int fr = lane & 15;
  const int fq = lane >> 4;

  const f32x4 fzero = {0.f, 0.f, 0.f, 0.f};
  f32x4 acc[4][4];
#pragma unroll
  for (int m = 0; m < 4; ++m)
#pragma unroll
    for (int n = 0; n < 4; ++n) acc[m][n] = fzero;

  for (int k0 = 0; k0 < HID; k0 += 64) {
    __syncthreads();
#pragma unroll
    for (int i = 0; i < 4; ++i) gload16(asrc + (size_t)i * 32 * HID + k0, &lA[srow + i * 32][scol]);
#pragma unroll
    for (int i = 0; i < 4; ++i) gload16(bsrc + (size_t)i * 32 * HID + k0, &lB[srow + i * 32][scol]);
    __syncthreads();
#pragma unroll
    for (int ks = 0; ks < 64; ks += 32) {
      const int kc = ks + (fq << 3);
      bf16x8 af[4], bf[4];
#pragma unroll
      for (int m = 0; m < 4; ++m) af[m] = *(const bf16x8*)&lA[wr + m * 16 + fr][kc];
#pragma unroll
      for (int n = 0; n < 4; ++n) bf[n] = *(const bf16x8*)&lB[wc + n * 16 + fr][kc];
#pragma unroll
      for (int m = 0; m < 4; ++m)
#pragma unroll
        for (int n = 0; n < 4; ++n)
          acc[m][n] = __builtin_amdgcn_mfma_f32_16x16x32_bf16(af[m], bf[n], acc[m][n], 0, 0, 0);
    }
  }
#pragma unroll
  for (int m = 0; m < 4; ++m) {
#pragma unroll
    for (int r = 0; r < 4; ++r) {
      const int row = mbase + wr + m * 16 + (fq << 2) + r;
      const int tok = rowidx[row];
      if (tok >= 0) {
        const float wgt = roww[row];
        float* op = out + (size_t)tok * DIM + nbase + wc + fr;
#pragma unroll
        for (int n = 0; n < 4; ++n) atomicAdd(&op[n * 16], acc[m][n][r] * wgt);
      }
    }
  }
}

extern "C" void kernel_launch(void* const* d_in, const int* in_sizes, int n_in,
                              void* d_out, int out_size, void* d_ws, size_t ws_size,
                              hipStream_t stream) {
  const float* x  = (const float*)d_in[0];
  const float* gw = (const float*)d_in[1];
  const float* wg = (const float*)d_in[2];
  const float* wu = (const float*)d_in[3];
  const float* wd = (const float*)d_in[4];
  float* out = (float*)d_out;
  char* ws = (char*)d_ws;

  u16* xb     = (u16*)(ws + 0);            // 32768*1024 bf16      = 64 MiB
  u16* wgb    = (u16*)(ws + 67108864);     // 8*1024*1024 bf16     = 16 MiB
  u16* wub    = (u16*)(ws + 83886080);
  u16* wdb    = (u16*)(ws + 100663296);
  u16* hbuf   = (u16*)(ws + 117440512);    // MCAP*1024 bf16       = 130 MiB
  int* rowidx = (int*)(ws + 253755392);    // MCAP
  float* roww = (float*)(ws + 254021632);  // MCAP
  int2* tokE  = (int2*)(ws + 254287872);   // NTOK
  float2* tokW= (float2*)(ws + 254550016); // NTOK
  int* tileE  = (int*)(ws + 254812160);    // MAXTILES
  int* tileB  = (int*)(ws + 254816256);    // MAXTILES
  int* ctrl   = (int*)(ws + 254820352);    // counts[8] cursors[8] off9[9] ntiles@28
  u16* zrow   = (u16*)(ws + 254820864);    // DIM zeros (gather pad page)

  hipMemsetAsync(out, 0, (size_t)out_size * 4, stream);
  hipMemsetAsync(ctrl, 0, 512, stream);
  hipMemsetAsync(rowidx, 0xFF, (size_t)MCAP * 4, stream);
  hipMemsetAsync(zrow, 0, DIM * 2, stream);

  cvt_kernel<<<4096, 256, 0, stream>>>(x,  xb,  NTOK * DIM / 8);
  cvt_kernel<<<4096, 256, 0, stream>>>(wg, wgb, NE * HID * DIM / 8);
  cvt_kernel<<<4096, 256, 0, stream>>>(wu, wub, NE * HID * DIM / 8);
  cvt_kernel<<<4096, 256, 0, stream>>>(wd, wdb, NE * DIM * HID / 8);
  router_kernel<<<1024, 256, 0, stream>>>(x, gw, tokE, tokW, ctrl);
  setup_kernel<<<1, 256, 0, stream>>>(ctrl, ctrl + 16, ctrl + 28, tileE, tileB);
  scatter_kernel<<<128, 256, 0, stream>>>(tokE, tokW, ctrl + 16, ctrl + 8, rowidx, roww);
  gemm1_kernel<<<dim3(8, MAXTILES), 256, 0, stream>>>(xb, wgb, wub, rowidx, ctrl + 28,
                                                      tileE, tileB, zrow, hbuf);
  gemm2_kernel<<<dim3(8, MAXTILES), 256, 0, stream>>>(hbuf, wdb, rowidx, roww, ctrl + 28,
                                                      tileE, tileB, out);
}

// Round 2
// 1187.912 us; speedup vs baseline: 1.2700x; 1.2700x over previous
//
#include <hip/hip_runtime.h>
#include <stdint.h>

#define DIM 1024
#define HID 1024
#define NE 8
#define NTOK 32768
#define MCAP (2*NTOK + NE*128)   /* 66560 rows: 65536 gathered + worst-case pad */
#define MAXTILES (MCAP/128)      /* 520 */

typedef unsigned short u16;
typedef short bf16x8 __attribute__((ext_vector_type(8)));
typedef float f32x4  __attribute__((ext_vector_type(4)));
typedef u16 u16x8 __attribute__((ext_vector_type(8)));

__device__ __forceinline__ u16 f2b(float f) {
  uint32_t u = __float_as_uint(f);
  return (u16)((u + 0x7fffu + ((u >> 16) & 1u)) >> 16);   // RNE f32->bf16
}
__device__ __forceinline__ float b2f(u16 v) {
  return __uint_as_float(((uint32_t)v) << 16);
}

__device__ __forceinline__ void gload16(const void* g, void* l) {
  __builtin_amdgcn_global_load_lds(
      (const __attribute__((address_space(1))) unsigned int*)g,
      (__attribute__((address_space(3))) unsigned int*)l, 16, 0, 0);
}

// ---------------- f32 -> bf16 bulk convert (8 elems/thread/iter) ----------------
__global__ __launch_bounds__(256) void cvt_kernel(const float* __restrict__ s,
                                                  u16* __restrict__ d, int n8) {
  int i = blockIdx.x * blockDim.x + threadIdx.x;
  int str = gridDim.x * blockDim.x;
  for (; i < n8; i += str) {
    const float4* sp = (const float4*)s + (size_t)i * 2;
    float4 a = sp[0], b = sp[1];
    u16x8 o;
    o[0] = f2b(a.x); o[1] = f2b(a.y); o[2] = f2b(a.z); o[3] = f2b(a.w);
    o[4] = f2b(b.x); o[5] = f2b(b.y); o[6] = f2b(b.z); o[7] = f2b(b.w);
    *(u16x8*)(d + (size_t)i * 8) = o;
  }
}

// ---------------- router: f64 logits, top-2, normalized sigmoid weights --------
__global__ __launch_bounds__(256) void router_kernel(
    const float* __restrict__ x, const float* __restrict__ gw,
    int2* __restrict__ tokE, float2* __restrict__ tokW, int* __restrict__ counts) {
  __shared__ int lcnt[NE];
  if (threadIdx.x < NE) lcnt[threadIdx.x] = 0;
  __syncthreads();
  const int wid = threadIdx.x >> 6, lane = threadIdx.x & 63;
  for (int j = 0; j < 8; ++j) {
    const int t = (blockIdx.x * 4 + wid) * 8 + j;
    const float4* xp = (const float4*)(x + (size_t)t * DIM);
    float4 xv[4];
#pragma unroll
    for (int c = 0; c < 4; ++c) xv[c] = xp[lane + 64 * c];
    double acc[NE];
#pragma unroll
    for (int e = 0; e < NE; ++e) {
      const float4* gp = (const float4*)(gw + e * DIM);
      double s = 0.0;
#pragma unroll
      for (int c = 0; c < 4; ++c) {
        float4 g = gp[lane + 64 * c];
        s += (double)xv[c].x * g.x + (double)xv[c].y * g.y +
             (double)xv[c].z * g.z + (double)xv[c].w * g.w;
      }
      acc[e] = s;
    }
#pragma unroll
    for (int e = 0; e < NE; ++e)
      for (int o = 32; o > 0; o >>= 1) acc[e] += __shfl_xor(acc[e], o);
    if (lane == 0) {
      int e0 = 0; double v0 = acc[0];
#pragma unroll
      for (int e = 1; e < NE; ++e) if (acc[e] > v0) { v0 = acc[e]; e0 = e; }
      int e1 = -1; double v1 = -1e300;
#pragma unroll
      for (int e = 0; e < NE; ++e) if (e != e0 && acc[e] > v1) { v1 = acc[e]; e1 = e; }
      float s0 = 1.f / (1.f + __expf(-(float)v0));
      float s1 = 1.f / (1.f + __expf(-(float)v1));
      float inv = 1.f / (s0 + s1 + 1e-9f);
      atomicAdd(&lcnt[e0], 1); atomicAdd(&lcnt[e1], 1);
      tokE[t] = make_int2(e0, e1);
      tokW[t] = make_float2(s0 * inv, s1 * inv);
    }
  }
  __syncthreads();
  if (threadIdx.x < NE) atomicAdd(&counts[threadIdx.x], lcnt[threadIdx.x]);
}

// ---------------- prefix (padded to 128) + tile table ----------------
__global__ void setup_kernel(const int* __restrict__ counts, int* __restrict__ off9,
                             int* __restrict__ ntiles, int* __restrict__ tileE,
                             int* __restrict__ tileB) {
  __shared__ int soff[NE + 1];
  if (threadIdx.x == 0) {
    int a = 0;
    for (int e = 0; e < NE; ++e) { soff[e] = a; a += ((counts[e] + 127) >> 7) << 7; }
    soff[NE] = a;
    for (int i = 0; i <= NE; ++i) off9[i] = soff[i];
    *ntiles = a >> 7;
  }
  __syncthreads();
  const int nt = soff[NE] >> 7;
  for (int i = threadIdx.x; i < nt; i += blockDim.x) {
    int r = i << 7, e = 0;
    while (r >= soff[e + 1]) ++e;
    tileE[i] = e; tileB[i] = r;
  }
}

// ---------------- scatter tokens into expert segments ----------------
__global__ __launch_bounds__(256) void scatter_kernel(
    const int2* __restrict__ tokE, const float2* __restrict__ tokW,
    const int* __restrict__ off9, int* __restrict__ cursors,
    int* __restrict__ rowidx, float* __restrict__ roww) {
  __shared__ int lcnt[NE], lbase[NE];
  if (threadIdx.x < NE) lcnt[threadIdx.x] = 0;
  __syncthreads();
  const int t = blockIdx.x * 256 + threadIdx.x;
  int2 e = tokE[t]; float2 w = tokW[t];
  int p0 = atomicAdd(&lcnt[e.x], 1);
  int p1 = atomicAdd(&lcnt[e.y], 1);
  __syncthreads();
  if (threadIdx.x < NE) lbase[threadIdx.x] = atomicAdd(&cursors[threadIdx.x], lcnt[threadIdx.x]);
  __syncthreads();
  int r0 = off9[e.x] + lbase[e.x] + p0;
  rowidx[r0] = t; roww[r0] = w.x;
  int r1 = off9[e.y] + lbase[e.y] + p1;
  rowidx[r1] = t; roww[r1] = w.y;
}

// ======== GEMM (m97 structure + both-sides XOR swizzle), gathered A ========
// C[128 x 128] per block; A rows gathered via rowidx; B row-major [N][K]; bf16 out.
__global__ __launch_bounds__(256) void gemm_gu_kernel(
    const u16* __restrict__ ab, const u16* __restrict__ wb,
    const int* __restrict__ rowidx, const int* __restrict__ ntiles,
    const int* __restrict__ tileE, const int* __restrict__ tileB,
    const u16* __restrict__ zrow, u16* __restrict__ outb) {
  if ((int)blockIdx.y >= *ntiles) return;
  const int e = tileE[blockIdx.y];
  const int mbase = tileB[blockIdx.y];
  const int nbase = blockIdx.x * 128;

  __shared__ __align__(16) u16 lA[128][64];
  __shared__ __align__(16) u16 lB[128][64];

  const int tid = threadIdx.x;
  const int srow = tid >> 3;                          // 0..31
  const int slin = (tid & 7) << 3;                    // linear LDS dest col (elems)
  const int ssw  = ((tid & 7) ^ (srow & 7)) << 3;     // swizzled global src col

  const u16* asrc[4];
#pragma unroll
  for (int i = 0; i < 4; ++i) {
    int tok = rowidx[mbase + srow + i * 32];
    asrc[i] = (tok >= 0) ? (ab + (size_t)tok * DIM + ssw) : (zrow + ssw);
  }
  const u16* bsrc = wb + (size_t)e * HID * DIM + (size_t)(nbase + srow) * DIM + ssw;

  const int wid = tid >> 6, lane = tid & 63;
  const int wr = (wid >> 1) << 6;
  const int wc = (wid & 1) << 6;
  const int fr = lane & 15;
  const int fq = lane >> 4;
  const int kx = (fr & 7) << 3;                       // read-side swizzle

  const f32x4 fzero = {0.f, 0.f, 0.f, 0.f};
  f32x4 acc[4][4];
#pragma unroll
  for (int m = 0; m < 4; ++m)
#pragma unroll
    for (int n = 0; n < 4; ++n) acc[m][n] = fzero;

  for (int k0 = 0; k0 < DIM; k0 += 64) {
    __syncthreads();
#pragma unroll
    for (int i = 0; i < 4; ++i) gload16(asrc[i] + k0, &lA[srow + i * 32][slin]);
#pragma unroll
    for (int i = 0; i < 4; ++i) gload16(bsrc + (size_t)i * 32 * DIM + k0, &lB[srow + i * 32][slin]);
    __syncthreads();
#pragma unroll
    for (int ks = 0; ks < 64; ks += 32) {
      const int kc = (ks + (fq << 3)) ^ kx;
      bf16x8 af[4], bfr[4];
#pragma unroll
      for (int m = 0; m < 4; ++m) af[m] = *(const bf16x8*)&lA[wr + m * 16 + fr][kc];
#pragma unroll
      for (int n = 0; n < 4; ++n) bfr[n] = *(const bf16x8*)&lB[wc + n * 16 + fr][kc];
#pragma unroll
      for (int m = 0; m < 4; ++m)
#pragma unroll
        for (int n = 0; n < 4; ++n)
          acc[m][n] = __builtin_amdgcn_mfma_f32_16x16x32_bf16(af[m], bfr[n], acc[m][n], 0, 0, 0);
    }
  }
#pragma unroll
  for (int m = 0; m < 4; ++m) {
#pragma unroll
    for (int r = 0; r < 4; ++r) {
      const int row = mbase + wr + m * 16 + (fq << 2) + r;
      u16* hp = outb + (size_t)row * HID + nbase + wc + fr;
#pragma unroll
      for (int n = 0; n < 4; ++n) hp[n * 16] = f2b(acc[m][n][r]);
    }
  }
}

// ---------------- elementwise: h = silu(g) * u * roww (in-place into g) -------
__global__ __launch_bounds__(256) void silu_mul_kernel(
    u16* __restrict__ g, const u16* __restrict__ u,
    const float* __restrict__ roww, int n8) {
  int i = blockIdx.x * blockDim.x + threadIdx.x;
  int str = gridDim.x * blockDim.x;
  for (; i < n8; i += str) {
    const int row = i >> 7;
    const float w = roww[row];
    u16x8 gv = *(const u16x8*)(g + (size_t)i * 8);
    u16x8 uv = *(const u16x8*)(u + (size_t)i * 8);
    u16x8 o;
#pragma unroll
    for (int j = 0; j < 8; ++j) {
      float gf = b2f(gv[j]), uf = b2f(uv[j]);
      float hv = gf * uf * w / (1.f + __expf(-gf));
      o[j] = f2b(hv);
    }
    *(u16x8*)(g + (size_t)i * 8) = o;
  }
}

// ======== GEMM-D: out[tok] += (h Wd^T) — contiguous A, atomic scatter ========
__global__ __launch_bounds__(256) void gemm_d_kernel(
    const u16* __restrict__ hbuf, const u16* __restrict__ wdb,
    const int* __restrict__ rowidx, const int* __restrict__ ntiles,
    const int* __restrict__ tileE, const int* __restrict__ tileB,
    float* __restrict__ out) {
  if ((int)blockIdx.y >= *ntiles) return;
  const int e = tileE[blockIdx.y];
  const int mbase = tileB[blockIdx.y];
  const int nbase = blockIdx.x * 128;

  __shared__ __align__(16) u16 lA[128][64];
  __shared__ __align__(16) u16 lB[128][64];

  const int tid = threadIdx.x;
  const int srow = tid >> 3;
  const int slin = (tid & 7) << 3;
  const int ssw  = ((tid & 7) ^ (srow & 7)) << 3;

  const u16* asrc = hbuf + (size_t)(mbase + srow) * HID + ssw;
  const u16* bsrc = wdb + (size_t)e * DIM * HID + (size_t)(nbase + srow) * HID + ssw;

  const int wid = tid >> 6, lane = tid & 63;
  const int wr = (wid >> 1) << 6;
  const int wc = (wid & 1) << 6;
  const int fr = lane & 15;
  const int fq = lane >> 4;
  const int kx = (fr & 7) << 3;

  const f32x4 fzero = {0.f, 0.f, 0.f, 0.f};
  f32x4 acc[4][4];
#pragma unroll
  for (int m = 0; m < 4; ++m)
#pragma unroll
    for (int n = 0; n < 4; ++n) acc[m][n] = fzero;

  for (int k0 = 0; k0 < HID; k0 += 64) {
    __syncthreads();
#pragma unroll
    for (int i = 0; i < 4; ++i) gload16(asrc + (size_t)i * 32 * HID + k0, &lA[srow + i * 32][slin]);
#pragma unroll
    for (int i = 0; i < 4; ++i) gload16(bsrc + (size_t)i * 32 * HID + k0, &lB[srow + i * 32][slin]);
    __syncthreads();
#pragma unroll
    for (int ks = 0; ks < 64; ks += 32) {
      const int kc = (ks + (fq << 3)) ^ kx;
      bf16x8 af[4], bfr[4];
#pragma unroll
      for (int m = 0; m < 4; ++m) af[m] = *(const bf16x8*)&lA[wr + m * 16 + fr][kc];
#pragma unroll
      for (int n = 0; n < 4; ++n) bfr[n] = *(const bf16x8*)&lB[wc + n * 16 + fr][kc];
#pragma unroll
      for (int m = 0; m < 4; ++m)
#pragma unroll
        for (int n = 0; n < 4; ++n)
          acc[m][n] = __builtin_amdgcn_mfma_f32_16x16x32_bf16(af[m], bfr[n], acc[m][n], 0, 0, 0);
    }
  }
#pragma unroll
  for (int m = 0; m < 4; ++m) {
#pragma unroll
    for (int r = 0; r < 4; ++r) {
      const int row = mbase + wr + m * 16 + (fq << 2) + r;
      const int tok = rowidx[row];
      if (tok >= 0) {
        float* op = out + (size_t)tok * DIM + nbase + wc + fr;
#pragma unroll
        for (int n = 0; n < 4; ++n) atomicAdd(&op[n * 16], acc[m][n][r]);
      }
    }
  }
}

extern "C" void kernel_launch(void* const* d_in, const int* in_sizes, int n_in,
                              void* d_out, int out_size, void* d_ws, size_t ws_size,
                              hipStream_t stream) {
  const float* x  = (const float*)d_in[0];
  const float* gw = (const float*)d_in[1];
  const float* wg = (const float*)d_in[2];
  const float* wu = (const float*)d_in[3];
  const float* wd = (const float*)d_in[4];
  float* out = (float*)d_out;
  char* ws = (char*)d_ws;

  constexpr size_t SZ_XB   = (size_t)NTOK * DIM * 2;        // 64 MiB
  constexpr size_t SZ_W    = (size_t)NE * HID * DIM * 2;    // 16 MiB
  constexpr size_t SZ_HB   = (size_t)MCAP * HID * 2;        // 130 MiB

  size_t off = 0;
  u16* xb     = (u16*)(ws + off); off += SZ_XB;
  u16* wgb    = (u16*)(ws + off); off += SZ_W;
  u16* wub    = (u16*)(ws + off); off += SZ_W;
  u16* wdb    = (u16*)(ws + off); off += SZ_W;
  u16* gbuf   = (u16*)(ws + off); off += SZ_HB;   // gate out, reused as h
  u16* ubuf   = (u16*)(ws + off); off += SZ_HB;   // up out
  int* rowidx = (int*)(ws + off); off += (size_t)MCAP * 4;
  float* roww = (float*)(ws + off); off += (size_t)MCAP * 4;
  int2* tokE  = (int2*)(ws + off); off += (size_t)NTOK * 8;
  float2* tokW= (float2*)(ws + off); off += (size_t)NTOK * 8;
  int* tileE  = (int*)(ws + off); off += 4096;
  int* tileB  = (int*)(ws + off); off += 4096;
  int* ctrl   = (int*)(ws + off); off += 512;     // counts[8] cursors[8] off9[9] ntiles@28
  u16* zrow   = (u16*)(ws + off); off += DIM * 2;

  hipMemsetAsync(out, 0, (size_t)out_size * 4, stream);
  hipMemsetAsync(ctrl, 0, 512, stream);
  hipMemsetAsync(rowidx, 0xFF, (size_t)MCAP * 4, stream);
  hipMemsetAsync(zrow, 0, DIM * 2, stream);

  cvt_kernel<<<4096, 256, 0, stream>>>(x,  xb,  NTOK * DIM / 8);
  cvt_kernel<<<4096, 256, 0, stream>>>(wg, wgb, NE * HID * DIM / 8);
  cvt_kernel<<<4096, 256, 0, stream>>>(wu, wub, NE * HID * DIM / 8);
  cvt_kernel<<<4096, 256, 0, stream>>>(wd, wdb, NE * DIM * HID / 8);
  router_kernel<<<1024, 256, 0, stream>>>(x, gw, tokE, tokW, ctrl);
  setup_kernel<<<1, 256, 0, stream>>>(ctrl, ctrl + 16, ctrl + 28, tileE, tileB);
  scatter_kernel<<<128, 256, 0, stream>>>(tokE, tokW, ctrl + 16, ctrl + 8, rowidx, roww);

  gemm_gu_kernel<<<dim3(8, MAXTILES), 256, 0, stream>>>(xb, wgb, rowidx, ctrl + 28,
                                                        tileE, tileB, zrow, gbuf);
  gemm_gu_kernel<<<dim3(8, MAXTILES), 256, 0, stream>>>(xb, wub, rowidx, ctrl + 28,
                                                        tileE, tileB, zrow, ubuf);
  silu_mul_kernel<<<2048, 256, 0, stream>>>(gbuf, ubuf, roww, MCAP * HID / 8);
  gemm_d_kernel<<<dim3(8, MAXTILES), 256, 0, stream>>>(gbuf, wdb, rowidx, ctrl + 28,
                                                       tileE, tileB, out);
}